// Round 4
// baseline (381.813 us; speedup 1.0000x reference)
//
#include <hip/hip_runtime.h>
#include <hip/hip_bf16.h>

typedef float f32x4 __attribute__((ext_vector_type(4)));
typedef __bf16 bf16x8 __attribute__((ext_vector_type(8)));
typedef __bf16 bf16x4 __attribute__((ext_vector_type(4)));

// async global->LDS, 16B per lane, wave-uniform LDS base (HW adds lane*16)
__device__ __forceinline__ void gld_lds16(const void* g, void* l) {
    __builtin_amdgcn_global_load_lds((const __attribute__((address_space(1))) void*)g,
                                     (__attribute__((address_space(3))) void*)l, 16, 0, 0);
}

// ---------------- f32 -> bf16 convert ----------------
__global__ __launch_bounds__(256) void cvt_kernel(const float* __restrict__ in,
                                                  __bf16* __restrict__ out, int n4) {
    int i = blockIdx.x * 256 + threadIdx.x;
    if (i >= n4) return;
    float4 v = reinterpret_cast<const float4*>(in)[i];
    bf16x4 o;
    o[0] = (__bf16)v.x; o[1] = (__bf16)v.y; o[2] = (__bf16)v.z; o[3] = (__bf16)v.w;
    reinterpret_cast<bf16x4*>(out)[i] = o;
}

// ---------------- GEMM  C = A(8192xK) * W(NxK)^T, K=1024 ----------------
// MODE 0: scatter epilogue into Q(*0.125)/K/V (B,H,T,D) bf16.  MODE 1: f32 C out (N=1024).
template <int MODE>
__global__ __launch_bounds__(256, 2)
void gemm_bt_kernel(const __bf16* __restrict__ A, const __bf16* __restrict__ W,
                    __bf16* __restrict__ Qo, __bf16* __restrict__ Ko, __bf16* __restrict__ Vo,
                    float* __restrict__ Co) {
    constexpr int K = 1024;
    __shared__ __align__(16) __bf16 As[128 * 64];
    __shared__ __align__(16) __bf16 Bs[128 * 64];
    const int tid = threadIdx.x;
    const int lane = tid & 63;
    const int wid = tid >> 6;
    const int bm = blockIdx.x, bn = blockIdx.y;
    const int wm = wid >> 1, wn = wid & 1;

    f32x4 acc[4][4] = {};

    const __bf16* Ab = A + (size_t)(bm * 128) * K;
    const __bf16* Wb = W + (size_t)(bn * 128) * K;

    for (int k0 = 0; k0 < K; k0 += 64) {
#pragma unroll
        for (int c = 0; c < 4; ++c) {
            const int chunk = c * 4 + wid;              // 16 chunks of 1KB per 16KB tile
            const int row = chunk * 8 + (lane >> 3);    // 8 rows per chunk
            const int colb = (lane & 7) * 16;           // byte offset within 128B row
            gld_lds16((const char*)(Ab + (size_t)row * K + k0) + colb, (char*)As + chunk * 1024);
            gld_lds16((const char*)(Wb + (size_t)row * K + k0) + colb, (char*)Bs + chunk * 1024);
        }
        __syncthreads();
        const int ro = lane & 15;
#pragma unroll
        for (int ks = 0; ks < 2; ++ks) {
            const int co = ks * 32 + (lane >> 4) * 8;
            bf16x8 a[4], b[4];
#pragma unroll
            for (int mt = 0; mt < 4; ++mt)
                a[mt] = *(const bf16x8*)(As + (wm * 64 + mt * 16 + ro) * 64 + co);
#pragma unroll
            for (int nt = 0; nt < 4; ++nt)
                b[nt] = *(const bf16x8*)(Bs + (wn * 64 + nt * 16 + ro) * 64 + co);
#pragma unroll
            for (int mt = 0; mt < 4; ++mt)
#pragma unroll
                for (int nt = 0; nt < 4; ++nt)
                    acc[mt][nt] = __builtin_amdgcn_mfma_f32_16x16x32_bf16(a[mt], b[nt], acc[mt][nt], 0, 0, 0);
        }
        __syncthreads();
    }

    // epilogue: C row = bm*128 + wm*64 + mt*16 + (lane>>4)*4 + r ; col = bn*128 + wn*64 + nt*16 + (lane&15)
#pragma unroll
    for (int mt = 0; mt < 4; ++mt) {
#pragma unroll
        for (int nt = 0; nt < 4; ++nt) {
            const int col = bn * 128 + wn * 64 + nt * 16 + (lane & 15);
            const int row0 = bm * 128 + wm * 64 + mt * 16 + (lane >> 4) * 4;
            if constexpr (MODE == 0) {
                const int s = col >> 10;          // 0=Q 1=K 2=V (uniform per block)
                const int h = (col >> 6) & 15;
                const int d = col & 63;
                __bf16* dst = (s == 0) ? Qo : (s == 1) ? Ko : Vo;
                const float scl = (s == 0) ? 0.125f : 1.0f;
#pragma unroll
                for (int r = 0; r < 4; ++r) {
                    const int m = row0 + r;
                    const int bb = m >> 11, t = m & 2047;
                    dst[(((size_t)bb * 16 + h) * 2048 + t) * 64 + d] = (__bf16)(acc[mt][nt][r] * scl);
                }
            } else {
#pragma unroll
                for (int r = 0; r < 4; ++r)
                    Co[(size_t)(row0 + r) * 1024 + col] = acc[mt][nt][r];
            }
        }
    }
}

// ---------------- causal flash attention ----------------
// grid: (T/128, B*H). 4 waves x 32 q-rows. K/V tiles of 64 in LDS (V transposed).
__global__ __launch_bounds__(256, 2)
void attn_kernel(const __bf16* __restrict__ Qg, const __bf16* __restrict__ Kg,
                 const __bf16* __restrict__ Vg, __bf16* __restrict__ Og) {
    constexpr int T = 2048;
    constexpr int LD = 72;  // padded row stride (144B: 16B-aligned, conflict-floor)
    __shared__ __align__(16) __bf16 Ks[64 * LD];
    __shared__ __align__(16) __bf16 Vs[64 * LD];      // transposed: Vs[d][k]
    __shared__ __align__(16) __bf16 Ps[4][32 * LD];   // per-wave P

    const int tid = threadIdx.x, lane = tid & 63, wid = tid >> 6;
    const int ro = lane & 15, go = lane >> 4;
    const int qb = blockIdx.x * 128;
    const int bh = blockIdx.y;
    const __bf16* Qh = Qg + (size_t)bh * T * 64;
    const __bf16* Kh = Kg + (size_t)bh * T * 64;
    const __bf16* Vh = Vg + (size_t)bh * T * 64;
    const int wq0 = qb + wid * 32;

    bf16x8 qf[2][2];
#pragma unroll
    for (int mt = 0; mt < 2; ++mt)
#pragma unroll
        for (int ks = 0; ks < 2; ++ks)
            qf[mt][ks] = *(const bf16x8*)(Qh + (size_t)(wq0 + mt * 16 + ro) * 64 + ks * 32 + go * 8);

    f32x4 acc[2][4] = {};
    float mrun[2][4], lrun[2][4];
#pragma unroll
    for (int mt = 0; mt < 2; ++mt)
#pragma unroll
        for (int r = 0; r < 4; ++r) { mrun[mt][r] = -1e30f; lrun[mt][r] = 0.f; }

    const int nkt = (qb >> 6) + 2;
    for (int kt = 0; kt < nkt; ++kt) {
        const int kt0 = kt * 64;
        // stage K row-major, V transposed (reg-staged; padded LDS)
#pragma unroll
        for (int c = 0; c < 2; ++c) {
            const int chunk = tid + c * 256;         // 512 chunks of 8 elems
            const int krow = chunk >> 3, cc = chunk & 7;
            bf16x8 kv = *(const bf16x8*)(Kh + (size_t)(kt0 + krow) * 64 + cc * 8);
            *(bf16x8*)(Ks + krow * LD + cc * 8) = kv;
            bf16x8 vv = *(const bf16x8*)(Vh + (size_t)(kt0 + krow) * 64 + cc * 8);
#pragma unroll
            for (int j = 0; j < 8; ++j) Vs[(cc * 8 + j) * LD + krow] = vv[j];
        }
        __syncthreads();
        if (kt0 <= wq0 + 31) {  // tile has unmasked cols for this wave
            f32x4 sc[2][4] = {};
#pragma unroll
            for (int ks = 0; ks < 2; ++ks) {
                const int co = ks * 32 + go * 8;
                bf16x8 kf[4];
#pragma unroll
                for (int ct = 0; ct < 4; ++ct)
                    kf[ct] = *(const bf16x8*)(Ks + (ct * 16 + ro) * LD + co);
#pragma unroll
                for (int mt = 0; mt < 2; ++mt)
#pragma unroll
                    for (int ct = 0; ct < 4; ++ct)
                        sc[mt][ct] = __builtin_amdgcn_mfma_f32_16x16x32_bf16(qf[mt][ks], kf[ct], sc[mt][ct], 0, 0, 0);
            }
            __bf16* Pw = &Ps[wid][0];
#pragma unroll
            for (int mt = 0; mt < 2; ++mt) {
#pragma unroll
                for (int r = 0; r < 4; ++r) {
                    const int qrow = wq0 + mt * 16 + go * 4 + r;
                    float pm = -1e30f;
#pragma unroll
                    for (int ct = 0; ct < 4; ++ct) {
                        const int kcol = kt0 + ct * 16 + ro;
                        float v = (kcol <= qrow) ? sc[mt][ct][r] : -1e30f;
                        sc[mt][ct][r] = v;
                        pm = fmaxf(pm, v);
                    }
                    pm = fmaxf(pm, __shfl_xor(pm, 1));
                    pm = fmaxf(pm, __shfl_xor(pm, 2));
                    pm = fmaxf(pm, __shfl_xor(pm, 4));
                    pm = fmaxf(pm, __shfl_xor(pm, 8));
                    const float mn = fmaxf(mrun[mt][r], pm);
                    const float scal = __expf(mrun[mt][r] - mn);
                    mrun[mt][r] = mn;
                    float ps = 0.f;
#pragma unroll
                    for (int ct = 0; ct < 4; ++ct) {
                        const float p = __expf(sc[mt][ct][r] - mn);
                        sc[mt][ct][r] = p;
                        ps += p;
                    }
                    ps += __shfl_xor(ps, 1);
                    ps += __shfl_xor(ps, 2);
                    ps += __shfl_xor(ps, 4);
                    ps += __shfl_xor(ps, 8);
                    lrun[mt][r] = lrun[mt][r] * scal + ps;
#pragma unroll
                    for (int dt = 0; dt < 4; ++dt) acc[mt][dt][r] *= scal;
#pragma unroll
                    for (int ct = 0; ct < 4; ++ct)
                        Pw[(mt * 16 + go * 4 + r) * LD + ct * 16 + ro] = (__bf16)sc[mt][ct][r];
                }
            }
            // PV: P as A-frags, V^T as B-frags (compiler inserts lgkmcnt for same-wave LDS RAW)
#pragma unroll
            for (int ks = 0; ks < 2; ++ks) {
                const int co = ks * 32 + go * 8;
                bf16x8 pf[2], vf[4];
#pragma unroll
                for (int mt = 0; mt < 2; ++mt)
                    pf[mt] = *(const bf16x8*)(Pw + (mt * 16 + ro) * LD + co);
#pragma unroll
                for (int dt = 0; dt < 4; ++dt)
                    vf[dt] = *(const bf16x8*)(Vs + (dt * 16 + ro) * LD + co);
#pragma unroll
                for (int mt = 0; mt < 2; ++mt)
#pragma unroll
                    for (int dt = 0; dt < 4; ++dt)
                        acc[mt][dt] = __builtin_amdgcn_mfma_f32_16x16x32_bf16(pf[mt], vf[dt], acc[mt][dt], 0, 0, 0);
            }
        }
        __syncthreads();
    }

    const int b = bh >> 4, h = bh & 15;
#pragma unroll
    for (int mt = 0; mt < 2; ++mt) {
#pragma unroll
        for (int r = 0; r < 4; ++r) {
            const int t = wq0 + mt * 16 + go * 4 + r;
            const float inv = 1.0f / lrun[mt][r];
#pragma unroll
            for (int dt = 0; dt < 4; ++dt)
                Og[((size_t)(b * 2048 + t)) * 1024 + h * 64 + dt * 16 + ro] = (__bf16)(acc[mt][dt][r] * inv);
        }
    }
}

extern "C" void kernel_launch(void* const* d_in, const int* in_sizes, int n_in,
                              void* d_out, int out_size, void* d_ws, size_t ws_size,
                              hipStream_t stream) {
    const float* query = (const float*)d_in[0];
    const float* w_in  = (const float*)d_in[3];
    const float* w_out = (const float*)d_in[4];
    float* out = (float*)d_out;

    char* ws = (char*)d_ws;
    size_t o = 0;
    __bf16* qin = (__bf16*)(ws + o); o += (size_t)8192 * 1024 * 2;   // 16 MB (reused as attn out)
    __bf16* wi  = (__bf16*)(ws + o); o += (size_t)3072 * 1024 * 2;   // 6 MB
    __bf16* wo  = (__bf16*)(ws + o); o += (size_t)1024 * 1024 * 2;   // 2 MB
    __bf16* Qd  = (__bf16*)(ws + o); o += (size_t)8192 * 1024 * 2;   // 16 MB (B,H,T,D)
    __bf16* Kd  = (__bf16*)(ws + o); o += (size_t)8192 * 1024 * 2;
    __bf16* Vd  = (__bf16*)(ws + o); o += (size_t)8192 * 1024 * 2;
    (void)ws_size; (void)in_sizes; (void)n_in; (void)out_size;

    cvt_kernel<<<8192, 256, 0, stream>>>(query, qin, 2097152);
    cvt_kernel<<<3072, 256, 0, stream>>>(w_in, wi, 786432);
    cvt_kernel<<<1024, 256, 0, stream>>>(w_out, wo, 262144);

    gemm_bt_kernel<0><<<dim3(64, 24), 256, 0, stream>>>(qin, wi, Qd, Kd, Vd, nullptr);
    attn_kernel<<<dim3(16, 64), 256, 0, stream>>>(Qd, Kd, Vd, qin);
    gemm_bt_kernel<1><<<dim3(64, 8), 256, 0, stream>>>(qin, wo, nullptr, nullptr, nullptr, out);
}

// Round 5
// 190.291 us; speedup vs baseline: 2.0065x; 2.0065x over previous
//
#include <hip/hip_runtime.h>
#include <hip/hip_bf16.h>

typedef float f32x4 __attribute__((ext_vector_type(4)));
typedef __bf16 bf16x8 __attribute__((ext_vector_type(8)));
typedef __bf16 bf16x4 __attribute__((ext_vector_type(4)));

// async global->LDS, 16B per lane, wave-uniform LDS base (HW adds lane*16)
__device__ __forceinline__ void gld_lds16(const void* g, void* l) {
    __builtin_amdgcn_global_load_lds((const __attribute__((address_space(1))) void*)g,
                                     (__attribute__((address_space(3))) void*)l, 16, 0, 0);
}

// ---------------- f32 -> bf16 convert ----------------
__global__ __launch_bounds__(256) void cvt_kernel(const float* __restrict__ in,
                                                  __bf16* __restrict__ out, int n4) {
    int i = blockIdx.x * 256 + threadIdx.x;
    if (i >= n4) return;
    float4 v = reinterpret_cast<const float4*>(in)[i];
    bf16x4 o;
    o[0] = (__bf16)v.x; o[1] = (__bf16)v.y; o[2] = (__bf16)v.z; o[3] = (__bf16)v.w;
    reinterpret_cast<bf16x4*>(out)[i] = o;
}

// ---------------- GEMM  C = A(8192xK) * W(NxK)^T, K=1024 ----------------
// MODE 0: scatter epilogue into Q(*0.125)/K/V (B,H,T,D) bf16.  MODE 1: f32 C out (N=1024).
template <int MODE>
__global__ __launch_bounds__(256, 2)
void gemm_bt_kernel(const __bf16* __restrict__ A, const __bf16* __restrict__ W,
                    __bf16* __restrict__ Qo, __bf16* __restrict__ Ko, __bf16* __restrict__ Vo,
                    float* __restrict__ Co) {
    constexpr int K = 1024;
    __shared__ __align__(16) __bf16 As[128 * 64];
    __shared__ __align__(16) __bf16 Bs[128 * 64];
    const int tid = threadIdx.x;
    const int lane = tid & 63;
    const int wid = tid >> 6;
    const int bm = blockIdx.x, bn = blockIdx.y;
    const int wm = wid >> 1, wn = wid & 1;

    f32x4 acc[4][4] = {};

    const __bf16* Ab = A + (size_t)(bm * 128) * K;
    const __bf16* Wb = W + (size_t)(bn * 128) * K;

    for (int k0 = 0; k0 < K; k0 += 64) {
#pragma unroll
        for (int c = 0; c < 4; ++c) {
            const int chunk = c * 4 + wid;              // 16 chunks of 1KB per 16KB tile
            const int row = chunk * 8 + (lane >> 3);    // 8 rows per chunk
            const int colb = (lane & 7) * 16;           // byte offset within 128B row
            gld_lds16((const char*)(Ab + (size_t)row * K + k0) + colb, (char*)As + chunk * 1024);
            gld_lds16((const char*)(Wb + (size_t)row * K + k0) + colb, (char*)Bs + chunk * 1024);
        }
        __syncthreads();
        const int ro = lane & 15;
#pragma unroll
        for (int ks = 0; ks < 2; ++ks) {
            const int co = ks * 32 + (lane >> 4) * 8;
            bf16x8 a[4], b[4];
#pragma unroll
            for (int mt = 0; mt < 4; ++mt)
                a[mt] = *(const bf16x8*)(As + (wm * 64 + mt * 16 + ro) * 64 + co);
#pragma unroll
            for (int nt = 0; nt < 4; ++nt)
                b[nt] = *(const bf16x8*)(Bs + (wn * 64 + nt * 16 + ro) * 64 + co);
#pragma unroll
            for (int mt = 0; mt < 4; ++mt)
#pragma unroll
                for (int nt = 0; nt < 4; ++nt)
                    acc[mt][nt] = __builtin_amdgcn_mfma_f32_16x16x32_bf16(a[mt], b[nt], acc[mt][nt], 0, 0, 0);
        }
        __syncthreads();
    }

    // epilogue: C row = bm*128 + wm*64 + mt*16 + (lane>>4)*4 + r ; col = bn*128 + wn*64 + nt*16 + (lane&15)
#pragma unroll
    for (int mt = 0; mt < 4; ++mt) {
#pragma unroll
        for (int nt = 0; nt < 4; ++nt) {
            const int col = bn * 128 + wn * 64 + nt * 16 + (lane & 15);
            const int row0 = bm * 128 + wm * 64 + mt * 16 + (lane >> 4) * 4;
            if constexpr (MODE == 0) {
                const int s = col >> 10;          // 0=Q 1=K 2=V (uniform per block)
                const int h = (col >> 6) & 15;
                const int d = col & 63;
                __bf16* dst = (s == 0) ? Qo : (s == 1) ? Ko : Vo;
                const float scl = (s == 0) ? 0.125f : 1.0f;
#pragma unroll
                for (int r = 0; r < 4; ++r) {
                    const int m = row0 + r;
                    const int bb = m >> 11, t = m & 2047;
                    dst[(((size_t)bb * 16 + h) * 2048 + t) * 64 + d] = (__bf16)(acc[mt][nt][r] * scl);
                }
            } else {
#pragma unroll
                for (int r = 0; r < 4; ++r)
                    Co[(size_t)(row0 + r) * 1024 + col] = acc[mt][nt][r];
            }
        }
    }
}

// ---------------- causal flash attention (swapped-QK^T softmax) ----------------
// grid: (8, B*H). Block x handles q-tiles {x, 15-x} (perfect causal balance: 34 K-tiles each).
// 4 waves x 32 q-rows. K row-major LDS; V transposed with XOR-swizzled column blocks.
// QK^T computed as mfma(K, Q) -> S^T: reg axis = k, lane axis = q. Softmax reduces
// 16 in-lane values + 2 shfl_xor (vs 64 bpermutes/tile before).
__global__ __launch_bounds__(256, 2)
void attn_kernel(const __bf16* __restrict__ Qg, const __bf16* __restrict__ Kg,
                 const __bf16* __restrict__ Vg, __bf16* __restrict__ Og) {
    constexpr int T = 2048;
    constexpr int LD = 72;  // padded row stride (144B)
    __shared__ __align__(16) __bf16 Ks[64 * LD];
    __shared__ __align__(16) __bf16 Vs[64 * LD];      // Vs[d][k] with k-block XOR swizzle
    __shared__ __align__(16) __bf16 Ps[4][32 * LD];   // per-wave P (A-frag layout)

    const int tid = threadIdx.x, lane = tid & 63, wid = tid >> 6;
    const int ro = lane & 15, go = lane >> 4;
    const int bh = blockIdx.y;
    const int b = bh >> 4, h = bh & 15;
    const __bf16* Qh = Qg + (size_t)bh * T * 64;
    const __bf16* Kh = Kg + (size_t)bh * T * 64;
    const __bf16* Vh = Vg + (size_t)bh * T * 64;
    __bf16* Pw = &Ps[wid][0];

    for (int half = 0; half < 2; ++half) {
        const int qblk = (half == 0) ? (int)blockIdx.x : 15 - (int)blockIdx.x;
        const int qb = qblk * 128;
        const int wq0 = qb + wid * 32;

        bf16x8 qf[2][2];
#pragma unroll
        for (int mt = 0; mt < 2; ++mt)
#pragma unroll
            for (int ks = 0; ks < 2; ++ks)
                qf[mt][ks] = *(const bf16x8*)(Qh + (size_t)(wq0 + mt * 16 + ro) * 64 + ks * 32 + go * 8);

        f32x4 acc[2][4] = {};
        float mrun[2] = {-1e30f, -1e30f};
        float lrun[2] = {0.f, 0.f};

        const int nkt = (qb >> 6) + 2;
        for (int kt = 0; kt < nkt; ++kt) {
            const int kt0 = kt * 64;
            // stage K row-major (vector), V transposed with swizzled k-blocks
#pragma unroll
            for (int c = 0; c < 2; ++c) {
                const int chunk = tid + c * 256;         // 512 chunks of 8 elems
                const int krow = chunk >> 3, cc = chunk & 7;
                bf16x8 kv = *(const bf16x8*)(Kh + (size_t)(kt0 + krow) * 64 + cc * 8);
                *(bf16x8*)(Ks + krow * LD + cc * 8) = kv;
                bf16x8 vv = *(const bf16x8*)(Vh + (size_t)(kt0 + krow) * 64 + cc * 8);
                const int pboff = (((krow >> 3) ^ cc) << 3) + (krow & 7);  // swizzled col
#pragma unroll
                for (int j = 0; j < 8; ++j) Vs[(cc * 8 + j) * LD + pboff] = vv[j];
            }
            __syncthreads();
            if (kt0 <= wq0 + 31) {  // tile has unmasked cols for this wave
                // QK^T swapped: st[mt][ct] = S^T tile; row(reg)=k-local, col(lane)=q-local
                f32x4 st[2][4] = {};
#pragma unroll
                for (int ks = 0; ks < 2; ++ks) {
                    const int co = ks * 32 + go * 8;
                    bf16x8 kf[4];
#pragma unroll
                    for (int ct = 0; ct < 4; ++ct)
                        kf[ct] = *(const bf16x8*)(Ks + (ct * 16 + ro) * LD + co);
#pragma unroll
                    for (int mt = 0; mt < 2; ++mt)
#pragma unroll
                        for (int ct = 0; ct < 4; ++ct)
                            st[mt][ct] = __builtin_amdgcn_mfma_f32_16x16x32_bf16(kf[ct], qf[mt][ks], st[mt][ct], 0, 0, 0);
                }
                float scal[2];
#pragma unroll
                for (int mt = 0; mt < 2; ++mt) {
                    const int qrow = wq0 + mt * 16 + ro;   // q owned by this lane
                    float pm = -1e30f;
#pragma unroll
                    for (int ct = 0; ct < 4; ++ct)
#pragma unroll
                        for (int rr = 0; rr < 4; ++rr) {
                            const int kcol = kt0 + ct * 16 + go * 4 + rr;
                            float v = (kcol <= qrow) ? st[mt][ct][rr] : -1e30f;
                            st[mt][ct][rr] = v;
                            pm = fmaxf(pm, v);
                        }
                    pm = fmaxf(pm, __shfl_xor(pm, 16));
                    pm = fmaxf(pm, __shfl_xor(pm, 32));
                    const float mn = fmaxf(mrun[mt], pm);
                    scal[mt] = __expf(mrun[mt] - mn);
                    mrun[mt] = mn;
                    float ps = 0.f;
#pragma unroll
                    for (int ct = 0; ct < 4; ++ct)
#pragma unroll
                        for (int rr = 0; rr < 4; ++rr) {
                            const float p = __expf(st[mt][ct][rr] - mn);
                            ps += p;
                            Pw[(mt * 16 + ro) * LD + ct * 16 + go * 4 + rr] = (__bf16)p;
                        }
                    ps += __shfl_xor(ps, 16);
                    ps += __shfl_xor(ps, 32);
                    lrun[mt] = lrun[mt] * scal[mt] + ps;
                    // redistribute rescale factor to PV C-layout rows (q%16 = go*4+r)
#pragma unroll
                    for (int r = 0; r < 4; ++r) {
                        const float sr = __shfl(scal[mt], (lane >> 4) * 4 + r);
#pragma unroll
                        for (int dt = 0; dt < 4; ++dt) acc[mt][dt][r] *= sr;
                    }
                }
                // PV: P A-frags from per-wave LDS, V^T B-frags from swizzled Vs
#pragma unroll
                for (int ks = 0; ks < 2; ++ks) {
                    const int co = ks * 32 + go * 8;
                    bf16x8 pf[2], vf[4];
#pragma unroll
                    for (int mt = 0; mt < 2; ++mt)
                        pf[mt] = *(const bf16x8*)(Pw + (mt * 16 + ro) * LD + co);
#pragma unroll
                    for (int dt = 0; dt < 4; ++dt) {
                        const int row = dt * 16 + ro;
                        const int pb2 = ((ks * 4 + go) ^ ((row >> 3) & 7)) << 3;
                        vf[dt] = *(const bf16x8*)(Vs + row * LD + pb2);
                    }
#pragma unroll
                    for (int mt = 0; mt < 2; ++mt)
#pragma unroll
                        for (int dt = 0; dt < 4; ++dt)
                            acc[mt][dt] = __builtin_amdgcn_mfma_f32_16x16x32_bf16(pf[mt], vf[dt], acc[mt][dt], 0, 0, 0);
                }
            }
            __syncthreads();
        }

#pragma unroll
        for (int mt = 0; mt < 2; ++mt) {
            const float inv = 1.0f / lrun[mt];
#pragma unroll
            for (int r = 0; r < 4; ++r) {
                const float ir = __shfl(inv, (lane >> 4) * 4 + r);
                const int t = wq0 + mt * 16 + go * 4 + r;
#pragma unroll
                for (int dt = 0; dt < 4; ++dt)
                    Og[((size_t)(b * 2048 + t)) * 1024 + h * 64 + dt * 16 + ro] = (__bf16)(acc[mt][dt][r] * ir);
            }
        }
    }
}

extern "C" void kernel_launch(void* const* d_in, const int* in_sizes, int n_in,
                              void* d_out, int out_size, void* d_ws, size_t ws_size,
                              hipStream_t stream) {
    const float* query = (const float*)d_in[0];
    const float* w_in  = (const float*)d_in[3];
    const float* w_out = (const float*)d_in[4];
    float* out = (float*)d_out;

    char* ws = (char*)d_ws;
    size_t o = 0;
    __bf16* qin = (__bf16*)(ws + o); o += (size_t)8192 * 1024 * 2;   // 16 MB (reused as attn out)
    __bf16* wi  = (__bf16*)(ws + o); o += (size_t)3072 * 1024 * 2;   // 6 MB
    __bf16* wo  = (__bf16*)(ws + o); o += (size_t)1024 * 1024 * 2;   // 2 MB
    __bf16* Qd  = (__bf16*)(ws + o); o += (size_t)8192 * 1024 * 2;   // 16 MB (B,H,T,D)
    __bf16* Kd  = (__bf16*)(ws + o); o += (size_t)8192 * 1024 * 2;
    __bf16* Vd  = (__bf16*)(ws + o); o += (size_t)8192 * 1024 * 2;
    (void)ws_size; (void)in_sizes; (void)n_in; (void)out_size;

    cvt_kernel<<<8192, 256, 0, stream>>>(query, qin, 2097152);
    cvt_kernel<<<3072, 256, 0, stream>>>(w_in, wi, 786432);
    cvt_kernel<<<1024, 256, 0, stream>>>(w_out, wo, 262144);

    gemm_bt_kernel<0><<<dim3(64, 24), 256, 0, stream>>>(qin, wi, Qd, Kd, Vd, nullptr);
    attn_kernel<<<dim3(8, 64), 256, 0, stream>>>(Qd, Kd, Vd, qin);
    gemm_bt_kernel<1><<<dim3(64, 8), 256, 0, stream>>>(qin, wo, nullptr, nullptr, nullptr, out);
}